// Round 3
// baseline (331.215 us; speedup 1.0000x reference)
//
#include <hip/hip_runtime.h>
#include <type_traits>

typedef unsigned short u16;
typedef __attribute__((ext_vector_type(8))) short short8;   // 8 bf16 (4 VGPRs) MFMA frag
typedef __attribute__((ext_vector_type(4))) float floatx4;  // MFMA acc

#define DEV __device__ __forceinline__

DEV float bf2f(u16 u) { return __uint_as_float(((unsigned)u) << 16); }
DEV u16 f2bf(float f) {                       // RNE fp32->bf16
  unsigned u = __float_as_uint(f);
  u += 0x7fffu + ((u >> 16) & 1u);
  return (u16)(u >> 16);
}
DEV void unpack8(uint4 v, float* f) {
  f[0] = __uint_as_float(v.x << 16); f[1] = __uint_as_float(v.x & 0xffff0000u);
  f[2] = __uint_as_float(v.y << 16); f[3] = __uint_as_float(v.y & 0xffff0000u);
  f[4] = __uint_as_float(v.z << 16); f[5] = __uint_as_float(v.z & 0xffff0000u);
  f[6] = __uint_as_float(v.w << 16); f[7] = __uint_as_float(v.w & 0xffff0000u);
}
DEV void async16(const void* g, void* lds) {  // 16B global->LDS DMA (lane*16 implicit)
  __builtin_amdgcn_global_load_lds((const __attribute__((address_space(1))) void*)g,
                                   (__attribute__((address_space(3))) void*)lds, 16, 0, 0);
}

#define MFMA16(d, x, y) d = __builtin_amdgcn_mfma_f32_16x16x32_bf16(x, y, d, 0, 0, 0)

// ---------------- fused prep: X fp32->bf16 convert (blocks 0..4095) +
//                  weight transpose-convert + bias3 pack (blocks 4096..8191) ----------------
__global__ __launch_bounds__(256)
void k_prep(const float* __restrict__ X, const float* __restrict__ Wq, const float* __restrict__ Wk,
            const float* __restrict__ Wv, const float* __restrict__ Wo,
            const float* __restrict__ bq, const float* __restrict__ bk, const float* __restrict__ bv,
            u16* __restrict__ Xb, u16* __restrict__ Wqkvt, u16* __restrict__ Wot,
            float* __restrict__ bias3) {
  if (blockIdx.x < 4096) {                  // ---- X convert ----
    size_t i = ((size_t)blockIdx.x * 256 + threadIdx.x) * 8;
    float4 a = *(const float4*)(X + i);
    float4 b = *(const float4*)(X + i + 4);
    union { u16 s[8]; uint4 v; } o;
    o.s[0]=f2bf(a.x); o.s[1]=f2bf(a.y); o.s[2]=f2bf(a.z); o.s[3]=f2bf(a.w);
    o.s[4]=f2bf(b.x); o.s[5]=f2bf(b.y); o.s[6]=f2bf(b.z); o.s[7]=f2bf(b.w);
    *(uint4*)(Xb + i) = o.v;
    return;
  }
  // ---- weight transpose-convert: rb = z*1024 + by*32 + bx ----
  const int rb = blockIdx.x - 4096;
  const int z = rb >> 10, bxx = rb & 31, byy = (rb >> 5) & 31;
  const float* src; u16* dst;
  switch (z) {
    case 0:  src = Wq; dst = Wqkvt;            break;
    case 1:  src = Wk; dst = Wqkvt + 1048576;  break;
    case 2:  src = Wv; dst = Wqkvt + 2097152;  break;
    default: src = Wo; dst = Wot;              break;
  }
  __shared__ float tile[32][33];
  int tx = threadIdx.x & 31, ty = threadIdx.x >> 5;  // 32 x 8
  int n0 = bxx * 32, k0 = byy * 32;
  #pragma unroll
  for (int i = 0; i < 32; i += 8) tile[ty + i][tx] = src[(size_t)(k0 + ty + i) * 1024 + n0 + tx];
  if (z == 3 && bxx == 0 && byy == 0) {
    for (int i = threadIdx.x; i < 3072; i += 256)
      bias3[i] = (i < 1024) ? bq[i] : (i < 2048 ? bk[i - 1024] : bv[i - 2048]);
  }
  __syncthreads();
  #pragma unroll
  for (int i = 0; i < 32; i += 8) dst[(size_t)(n0 + ty + i) * 1024 + k0 + tx] = f2bf(tile[tx][ty + i]);
}

// ---------------- 256x128 B-in-register bf16 GEMM, BK=64, 1 barrier/tile ----------------
// Theory (r2 post-mortem): the 4-phase LDS-both-operands schedule was LDS-BW and
// barrier-granularity bound (20 b128/wave/tile, 4 barriers, 8 MFMA/barrier). Here:
//  - waves 4M x 2N -> per-wave 64x64 output, A reads drop to 8 b128/wave/tile;
//  - B operand is loaded global->VGPR directly (per-tile B slice is 16 KB, L1/L2-hot;
//    shared by 4 waves), double-set (bA/bB) prefetched one tile ahead;
//  - LDS holds only A (64 KiB double-buffer), staged via global_load_lds one tile ahead;
//  - ONE barrier per K-tile; counted vmcnt ledger: per tile issue A(t+1)x4 then
//    B(t+1)x8 (order pinned by sched_barrier at the two issue points); before the
//    tile-end barrier s_waitcnt vmcnt(8) -> A(t+1) landed, B(t+1) in flight. The
//    compiler auto-inserts the wait for B(t) consumption (oldest in FIFO). Never
//    vmcnt(0) inside the loop.
// K-accumulation order per output element is identical to prior rounds (ascending
// 32-k chunks) -> bitwise-identical results.
DEV void gemm_tile(const u16* __restrict__ A, size_t aoff, int K, int kt1E,
                   u16* __restrict__ smNext, const u16* __restrict__ As0,
                   const u16* __restrict__ Bp,
                   short8 (&BU)[4][2], short8 (&BL)[4][2], floatx4 (&acc)[4][4],
                   int mg, int lr, int ch0, int ch1, int dstE) {
  short8 a[4][2];
  #pragma unroll
  for (int i = 0; i < 4; ++i) {                       // 8x ds_read_b128 (swizzled)
    const int row = (mg << 6) + (i << 4) + lr;
    a[i][0] = *(const short8*)&As0[(row << 6) + ch0];
    a[i][1] = *(const short8*)&As0[(row << 6) + ch1];
  }
  #pragma unroll
  for (int r = 0; r < 4; ++r)                         // stage A(t+1) -> other buffer
    async16(A + aoff + (size_t)((r) << 6) * K + kt1E, smNext + (r << 12) + dstE);
  __builtin_amdgcn_sched_barrier(0);                  // pin: staging before B loads
  #pragma unroll
  for (int j = 0; j < 4; ++j)                         // prefetch B(t+1) -> regs
    #pragma unroll
    for (int s = 0; s < 2; ++s)
      BL[j][s] = *(const short8*)(Bp + (size_t)(j << 4) * K + kt1E + (s << 5));
  __builtin_amdgcn_sched_barrier(0);                  // pin: B loads before MFMA block
  __builtin_amdgcn_s_setprio(1);
  #pragma unroll
  for (int i = 0; i < 4; ++i)
    #pragma unroll
    for (int j = 0; j < 4; ++j) {
      MFMA16(acc[i][j], a[i][0], BU[j][0]);           // k-lo
      MFMA16(acc[i][j], a[i][1], BU[j][1]);           // k-hi
    }
  __builtin_amdgcn_s_setprio(0);
  asm volatile("s_waitcnt vmcnt(8)" ::: "memory");    // A(t+1) landed; B(t+1) in flight
  __builtin_amdgcn_s_barrier();
  __builtin_amdgcn_sched_barrier(0);                  // no ds_read hoisting above barrier
}

template <typename OutT>
__global__ __launch_bounds__(512, 2)
void k_gemm_breg(const u16* __restrict__ A, const u16* __restrict__ B,
                 const float* __restrict__ bias, OutT* __restrict__ C,
                 int M, int N, int K) {
  __shared__ __align__(16) u16 sm[2][16384];   // A only: [buf][256 rows][64 k] = 64 KiB
  const int t = threadIdx.x;
  const int w = t >> 6, lane = t & 63;
  const int lr = lane & 15, q = lane >> 4, l7 = lr & 7;

  // T1: XCD-bijective swizzle (grid is a multiple of 8: 768 / 256)
  const int cpx = (int)gridDim.x >> 3;
  const int wg = ((int)blockIdx.x & 7) * cpx + ((int)blockIdx.x >> 3);
  const int nbx = N >> 7;
  const int by = wg / nbx, bx = wg - by * nbx;
  const int m0 = by << 8, n0 = bx << 7;

  // A staging: thread t covers row srow of each 64-row round; physical chunk p=t&7
  // holds logical k-chunk j = p ^ (row&7)  (pre-swizzled global source, rule #21)
  const int srow = t >> 3;
  const int sj8 = (((t & 7) ^ (srow & 7)) << 3);
  const size_t aoff = (size_t)(m0 + srow) * K + sj8;
  const int dstE = w << 9;                   // wave-uniform LDS base (elems)

  // A frag de-swizzle: logical chunk (s*4+q) lives at ((s*4+q)^(row&7)); row&7==lr&7
  const int ch0 = ((q ^ l7) << 3);
  const int ch1 = (((4 | q) ^ l7) << 3);

  const int mg = w >> 1, ng = w & 1;         // 4M x 2N wave grid, 64x64 per wave
  const u16* Bp = B + (size_t)(n0 + (ng << 6) + lr) * K + (q << 3);

  const int NT = K >> 6;                     // 16 (even; loop unrolled by 2)

  floatx4 acc[4][4];
  #pragma unroll
  for (int i = 0; i < 4; ++i)
    #pragma unroll
    for (int j = 0; j < 4; ++j)
      #pragma unroll
      for (int k = 0; k < 4; ++k) acc[i][j][k] = 0.f;

  short8 bA[4][2], bB[4][2];

  // prologue: stage A(0) -> buf0; load B(0) -> bA; wait A(0) only (vmcnt(8))
  #pragma unroll
  for (int r = 0; r < 4; ++r)
    async16(A + aoff + (size_t)(r << 6) * K, &sm[0][(r << 12) + dstE]);
  __builtin_amdgcn_sched_barrier(0);
  #pragma unroll
  for (int j = 0; j < 4; ++j)
    #pragma unroll
    for (int s = 0; s < 2; ++s)
      bA[j][s] = *(const short8*)(Bp + (size_t)(j << 4) * K + (s << 5));
  __builtin_amdgcn_sched_barrier(0);
  asm volatile("s_waitcnt vmcnt(8)" ::: "memory");
  __builtin_amdgcn_s_barrier();
  __builtin_amdgcn_sched_barrier(0);

  for (int kt = 0; kt < NT; kt += 2) {
    const int k1 = ((kt + 1 < NT) ? kt + 1 : NT - 1) << 6;   // clamp keeps ledger uniform
    const int k2 = ((kt + 2 < NT) ? kt + 2 : NT - 1) << 6;
    gemm_tile(A, aoff, K, k1, &sm[1][0], &sm[0][0], Bp, bA, bB, acc, mg, lr, ch0, ch1, dstE);
    gemm_tile(A, aoff, K, k2, &sm[0][0], &sm[1][0], Bp, bB, bA, acc, mg, lr, ch0, ch1, dstE);
  }
  asm volatile("s_waitcnt vmcnt(0)" ::: "memory");     // drain clamped tail stages

  // epilogue: C/D layout col = lane&15, row = (lane>>4)*4 + reg
  const int wrm = m0 + (mg << 6);
  const int wcn = n0 + (ng << 6);
  const int lq = q << 2;
  #pragma unroll
  for (int j = 0; j < 4; ++j) {
    const int cn = wcn + (j << 4) + lr;
    const float bv = bias[cn];
    #pragma unroll
    for (int i = 0; i < 4; ++i) {
      const int rm = wrm + (i << 4) + lq;
      #pragma unroll
      for (int rr = 0; rr < 4; ++rr) {
        float v = acc[i][j][rr] + bv;
        if constexpr (std::is_same<OutT, u16>::value) C[(size_t)(rm + rr) * N + cn] = f2bf(v);
        else                                          C[(size_t)(rm + rr) * N + cn] = v;
      }
    }
  }
}

// ---------------- Gram partials via MFMA + qsum partials ----------------
__global__ __launch_bounds__(256)
void k_gpart2(const u16* __restrict__ QKV, float* __restrict__ Gpart, float* __restrict__ qpart) {
  const int chunk = blockIdx.x;            // 0..7 (256 a each)
  const int nh = blockIdx.y;               // 0..63
  const int n = nh >> 4, h = nh & 15;
  const int t = threadIdx.x, w = t >> 6, lane = t & 63;
  const int lr = lane & 15, lko = (lane >> 4) << 3;

  __shared__ __align__(16) u16 Qt[64 * 264];   // x-major, a-stride-padded (33.8 KB)
  __shared__ float red[256];

  // transpose-in: thread t <-> a_local = t; reads its full 64-dim Q row (8x uint4, 128 B)
  const int a = chunk * 256 + t;
  const uint4* qp = (const uint4*)(QKV + (size_t)(n * 2048 + h * 128 + (a >> 4)) * 3072 + ((t & 15) << 6));
  union { u16 s[8]; uint4 v; } qv[8];
  #pragma unroll
  for (int j = 0; j < 8; ++j) qv[j].v = qp[j];
  #pragma unroll
  for (int j = 0; j < 8; ++j)
    #pragma unroll
    for (int e = 0; e < 8; ++e)
      Qt[(j * 8 + e) * 264 + t] = qv[j].s[e];   // writes: consecutive a per lane -> 2-way, free
  __syncthreads();

  // qsum partial: thread (x = t&63, c = t>>6) sums Qt[x][c*64 .. +63]
  {
    const int x = t & 63, c = t >> 6;
    const u16* base = &Qt[x * 264 + c * 64];
    float s = 0.f;
    #pragma unroll
    for (int k = 0; k < 8; ++k) {
      float f[8]; unpack8(*(const uint4*)(base + k * 8), f);
      #pragma unroll
      for (int e = 0; e < 8; ++e) s += f[e];
    }
    red[t] = s;
  }
  __syncthreads();
  if (t < 64)
    qpart[((size_t)nh * 8 + chunk) * 64 + t] = red[t] + red[t + 64] + red[t + 128] + red[t + 192];

  // Gram: K-loop over 256 a in 8 steps of 32; wave w owns C tile-row i=w
  floatx4 acc[4];
  #pragma unroll
  for (int j = 0; j < 4; ++j)
    #pragma unroll
    for (int k = 0; k < 4; ++k) acc[j][k] = 0.f;
  for (int ks = 0; ks < 8; ++ks) {
    short8 f[4];
    #pragma unroll
    for (int i = 0; i < 4; ++i) f[i] = *(const short8*)&Qt[((i << 4) + lr) * 264 + (ks << 5) + lko];
    #pragma unroll
    for (int j = 0; j < 4; ++j)
      acc[j] = __builtin_amdgcn_mfma_f32_16x16x32_bf16(f[w], f[j], acc[j], 0, 0, 0);
  }
  float* o = Gpart + ((size_t)nh * 8 + chunk) * 4096;
  const int quad = lane >> 4;
  #pragma unroll
  for (int j = 0; j < 4; ++j)
    #pragma unroll
    for (int r = 0; r < 4; ++r)
      o[((w << 4) + (quad << 2) + r) * 64 + (j << 4) + lr] = acc[j][r];
}

// ---------------- fused: G-reduce -> U = K*G (MFMA, LDS) -> Taylor denom/diag -> mid = diag*V ----
__global__ __launch_bounds__(256)
void k_kgd(const u16* __restrict__ QKV, const float* __restrict__ Gpart,
           const float* __restrict__ qpart, u16* __restrict__ mid) {
  const int chunk = blockIdx.x;            // 0..7 (256 a each)
  const int nh = blockIdx.y;               // 0..63
  const int n = nh >> 4, h = nh & 15;
  const int t = threadIdx.x, w = t >> 6, lane = t & 63;
  const int lr = lane & 15, lko = (lane >> 4) << 3;

  __shared__ u16 Gs[4096];                 // bf16 G_h, 64x64 (8 KB)
  __shared__ __align__(16) u16 Us[256 * 72];  // bf16 U rows, padded stride 72 (36.9 KB)
  __shared__ float qs[64];

  // --- stage 0: reduce Gpart (8 chunks) -> Gs bf16; load qs ---
  const float* gp0 = Gpart + (size_t)nh * 8 * 4096;
  #pragma unroll
  for (int i = 0; i < 16; ++i) {
    int e = (i << 8) + t;
    float s = 0.f;
    #pragma unroll
    for (int c = 0; c < 8; ++c) s += gp0[c * 4096 + e];
    Gs[e] = f2bf(s);
  }
  if (t < 64) {
    float s = 0.f;
    #pragma unroll
    for (int rc = 0; rc < 8; ++rc) s += qpart[((size_t)nh * 8 + rc) * 64 + t];
    qs[t] = s;
  }
  __syncthreads();

  // --- stage 1: U = K * G via MFMA (each wave: 64 a-rows x 64 cols) ---
  short8 af[4][2], bfr[4][2];
  #pragma unroll
  for (int i = 0; i < 4; ++i) {
    const int arow = chunk * 16 + (w << 2) + i;         // (a>>4) within head
    const u16* kp = QKV + (size_t)(n * 2048 + h * 128 + arow) * 3072 + 1024 + lr * 64;
    #pragma unroll
    for (int s = 0; s < 2; ++s) af[i][s] = *(const short8*)(kp + s * 32 + lko);
  }
  #pragma unroll
  for (int j = 0; j < 4; ++j)
    #pragma unroll
    for (int s = 0; s < 2; ++s)
      bfr[j][s] = *(const short8*)&Gs[((j << 4) + lr) * 64 + s * 32 + lko];
  floatx4 acc[4][4];
  #pragma unroll
  for (int i = 0; i < 4; ++i)
    #pragma unroll
    for (int j = 0; j < 4; ++j)
      #pragma unroll
      for (int k = 0; k < 4; ++k) acc[i][j][k] = 0.f;
  #pragma unroll
  for (int s = 0; s < 2; ++s)
    #pragma unroll
    for (int i = 0; i < 4; ++i)
      #pragma unroll
      for (int j = 0; j < 4; ++j)
        acc[i][j] = __builtin_amdgcn_mfma_f32_16x16x32_bf16(af[i][s], bfr[j][s], acc[i][j], 0, 0, 0);
  const int rq = (lane >> 4) << 2;
  #pragma unroll
  for (int i = 0; i < 4; ++i)
    #pragma unroll
    for (int j = 0; j < 4; ++j)
      #pragma unroll
      for (int r = 0; r < 4; ++r) {
        int a_local = (w << 6) + (i << 4) + rq + r;     // 0..255
        Us[a_local * 72 + (j << 4) + lr] = f2bf(acc[i][j][r]);
      }
  __syncthreads();

  // --- stage 2: per-thread a: Taylor denom + diag; mid = diag * V ---
  const int b = chunk * 256 + t;           // a within head
  const int R = n * 2048 + h * 128 + (b >> 4);
  const u16* row = QKV + (size_t)R * 3072 + ((b & 15) << 6);
  const uint4* qp = (const uint4*)row;
  const uint4* kp = (const uint4*)(row + 1024);
  const uint4* vp = (const uint4*)(row + 2048);
  const uint4* up = (const uint4*)&Us[t * 72];
  float sbb = 0.f, s1 = 0.f, quad = 0.f;
  #pragma unroll
  for (int xo = 0; xo < 8; ++xo) {
    float kx[8], qx[8], ux[8];
    unpack8(kp[xo], kx); unpack8(qp[xo], qx); unpack8(up[xo], ux);
    #pragma unroll
    for (int xi = 0; xi < 8; ++xi) {
      sbb  += qx[xi] * kx[xi];
      quad += ux[xi] * kx[xi];
      s1   += qs[xo * 8 + xi] * kx[xi];
    }
  }
  const float c1 = 0.0009765625f;  // 1/1024
  float denom = 2048.f + s1 * c1 + 0.5f * quad * c1 * c1;
  float d = expf(sbb * c1) / denom;
  u16* mp = mid + (size_t)R * 1024 + ((b & 15) << 6);
  #pragma unroll
  for (int xo = 0; xo < 8; ++xo) {
    float f[8]; unpack8(vp[xo], f);
    union { u16 s[8]; uint4 v; } o;
    #pragma unroll
    for (int k = 0; k < 8; ++k) o.s[k] = f2bf(f[k] * d);
    *(uint4*)(mp + xo * 8) = o.v;
  }
}

// ---------------- launch ----------------
extern "C" void kernel_launch(void* const* d_in, const int* in_sizes, int n_in,
                              void* d_out, int out_size, void* d_ws, size_t ws_size,
                              hipStream_t stream) {
  (void)in_sizes; (void)n_in; (void)out_size; (void)ws_size;
  const float* X  = (const float*)d_in[0];
  const float* Wq = (const float*)d_in[1];
  const float* bq = (const float*)d_in[2];
  const float* Wk = (const float*)d_in[3];
  const float* bk = (const float*)d_in[4];
  const float* Wv = (const float*)d_in[5];
  const float* bv = (const float*)d_in[6];
  const float* Wo = (const float*)d_in[7];
  const float* bo = (const float*)d_in[8];
  float* out = (float*)d_out;
  char* ws = (char*)d_ws;

  u16*   Xb    = (u16*)(ws + 0);                 // 16 MB (dead after QKV GEMM)
  u16*   mid   = (u16*)(ws + 0);                 // overlays Xb (written after Xb is dead)
  u16*   Wqkvt = (u16*)(ws + 16777216);          //  6 MB
  u16*   Wot   = (u16*)(ws + 23068672);          //  2 MB
  float* bias3 = (float*)(ws + 25165824);        // 12 KB
  u16*   QKV   = (u16*)(ws + 25182208);          // 48 MB (8192 x [Q|K|V])
  float* Gpart = (float*)(ws + 75513856);        //  8 MB
  float* qpart = (float*)(ws + 83902464);        // 128 KB   -> end ~80 MB

  k_prep<<<8192, 256, 0, stream>>>(X, Wq, Wk, Wv, Wo, bq, bk, bv, Xb, Wqkvt, Wot, bias3);
  // QKV GEMM: 256x128 tiles -> grid (8192/256)*(3072/128) = 768 = exactly 3 rounds of 256 CUs
  k_gemm_breg<u16><<<768, 512, 0, stream>>>(Xb, Wqkvt, bias3, QKV, 8192, 3072, 1024);
  k_gpart2<<<dim3(8, 64), 256, 0, stream>>>(QKV, Gpart, qpart);
  k_kgd<<<dim3(8, 64), 256, 0, stream>>>(QKV, Gpart, qpart, mid);
  // out-projection: grid (8192/256)*(1024/128) = 256 = exactly 1 round
  k_gemm_breg<float><<<256, 512, 0, stream>>>(mid, Wot, bo, out, 8192, 1024, 1024);
}

// Round 4
// 237.684 us; speedup vs baseline: 1.3935x; 1.3935x over previous
//
#include <hip/hip_runtime.h>
#include <type_traits>

typedef unsigned short u16;
typedef __attribute__((ext_vector_type(8))) short short8;   // 8 bf16 (4 VGPRs) MFMA frag
typedef __attribute__((ext_vector_type(4))) float floatx4;  // MFMA acc

#define DEV __device__ __forceinline__

DEV float bf2f(u16 u) { return __uint_as_float(((unsigned)u) << 16); }
DEV u16 f2bf(float f) {                       // RNE fp32->bf16
  unsigned u = __float_as_uint(f);
  u += 0x7fffu + ((u >> 16) & 1u);
  return (u16)(u >> 16);
}
DEV void unpack8(uint4 v, float* f) {
  f[0] = __uint_as_float(v.x << 16); f[1] = __uint_as_float(v.x & 0xffff0000u);
  f[2] = __uint_as_float(v.y << 16); f[3] = __uint_as_float(v.y & 0xffff0000u);
  f[4] = __uint_as_float(v.z << 16); f[5] = __uint_as_float(v.z & 0xffff0000u);
  f[6] = __uint_as_float(v.w << 16); f[7] = __uint_as_float(v.w & 0xffff0000u);
}
DEV void async16(const void* g, void* lds) {  // 16B global->LDS DMA (lane*16 implicit)
  __builtin_amdgcn_global_load_lds((const __attribute__((address_space(1))) void*)g,
                                   (__attribute__((address_space(3))) void*)lds, 16, 0, 0);
}

#define MFMA16(d, x, y) d = __builtin_amdgcn_mfma_f32_16x16x32_bf16(x, y, d, 0, 0, 0)

// ---------------- fused prep: X fp32->bf16 convert (blocks 0..4095) +
//                  weight transpose-convert + bias3 pack (blocks 4096..8191) ----------------
__global__ __launch_bounds__(256)
void k_prep(const float* __restrict__ X, const float* __restrict__ Wq, const float* __restrict__ Wk,
            const float* __restrict__ Wv, const float* __restrict__ Wo,
            const float* __restrict__ bq, const float* __restrict__ bk, const float* __restrict__ bv,
            u16* __restrict__ Xb, u16* __restrict__ Wqkvt, u16* __restrict__ Wot,
            float* __restrict__ bias3) {
  if (blockIdx.x < 4096) {                  // ---- X convert ----
    size_t i = ((size_t)blockIdx.x * 256 + threadIdx.x) * 8;
    float4 a = *(const float4*)(X + i);
    float4 b = *(const float4*)(X + i + 4);
    union { u16 s[8]; uint4 v; } o;
    o.s[0]=f2bf(a.x); o.s[1]=f2bf(a.y); o.s[2]=f2bf(a.z); o.s[3]=f2bf(a.w);
    o.s[4]=f2bf(b.x); o.s[5]=f2bf(b.y); o.s[6]=f2bf(b.z); o.s[7]=f2bf(b.w);
    *(uint4*)(Xb + i) = o.v;
    return;
  }
  // ---- weight transpose-convert: rb = z*1024 + by*32 + bx ----
  const int rb = blockIdx.x - 4096;
  const int z = rb >> 10, bxx = rb & 31, byy = (rb >> 5) & 31;
  const float* src; u16* dst;
  switch (z) {
    case 0:  src = Wq; dst = Wqkvt;            break;
    case 1:  src = Wk; dst = Wqkvt + 1048576;  break;
    case 2:  src = Wv; dst = Wqkvt + 2097152;  break;
    default: src = Wo; dst = Wot;              break;
  }
  __shared__ float tile[32][33];
  int tx = threadIdx.x & 31, ty = threadIdx.x >> 5;  // 32 x 8
  int n0 = bxx * 32, k0 = byy * 32;
  #pragma unroll
  for (int i = 0; i < 32; i += 8) tile[ty + i][tx] = src[(size_t)(k0 + ty + i) * 1024 + n0 + tx];
  if (z == 3 && bxx == 0 && byy == 0) {
    for (int i = threadIdx.x; i < 3072; i += 256)
      bias3[i] = (i < 1024) ? bq[i] : (i < 2048 ? bk[i - 1024] : bv[i - 2048]);
  }
  __syncthreads();
  #pragma unroll
  for (int i = 0; i < 32; i += 8) dst[(size_t)(n0 + ty + i) * 1024 + k0 + tx] = f2bf(tile[tx][ty + i]);
}

// ---------------- 256x192 2-phase bf16 GEMM (QKV), BK=64 ----------------
// r3 post-mortem: B-in-register collapsed prefetch depth below HBM latency -> revert
// to the verified r2 LDS-double-buffer idioms; fix the r2 limiter (LDS:MFMA ratio of
// the 128x32 wave tile) geometrically. Wave tile 128x48 (2M x 4N): 14 b128 reads /
// 48 MFMA per wave-tile; 2 barriers/tile; grid 32x16 = 512 = exactly 2 rounds.
// Ledger: ph1 stages A(t+1)x4 -> buf[cur^1]; ph2 stages B(t+2)x3 -> buf[cur] (all B
// reads of buf[cur] completed before ph1 barrier); tile-end s_waitcnt vmcnt(3) drains
// B(t+1)+A(t+1), leaves B(t+2) in flight. Never vmcnt(0) in the loop; tail clamps.
// K-accumulation order per output element identical to prior rounds.
template <typename OutT>
__global__ __launch_bounds__(512, 2)
void k_gemm_192(const u16* __restrict__ A, const u16* __restrict__ B,
                const float* __restrict__ bias, OutT* __restrict__ C,
                int M, int N, int K) {
  __shared__ __align__(16) u16 smA[2][2][8192];   // [buf][A rows 0-127 | 128-255][128*64]
  __shared__ __align__(16) u16 smB[2][12288];     // [buf][192 rows * 64 k]
  const int t = threadIdx.x;
  const int w = t >> 6, lane = t & 63;
  const int lr = lane & 15, q = lane >> 4, l7 = lr & 7;

  // T1: XCD-bijective swizzle (grid 512, multiple of 8)
  const int cpx = (int)gridDim.x >> 3;
  const int wg = ((int)blockIdx.x & 7) * cpx + ((int)blockIdx.x >> 3);
  const int nbx = N / 192;
  const int by = wg / nbx, bx = wg - by * nbx;
  const int m0 = by << 8, n0 = bx * 192;

  // staging: thread t covers row srow of each 64-row round; physical chunk p=t&7
  // holds logical k-chunk j = p ^ (row&7) -> pre-swizzled global source (rule #21)
  const int srow = t >> 3;
  const int sj8 = (((t & 7) ^ (srow & 7)) << 3);
  const size_t aoff = (size_t)(m0 + srow) * K + sj8;
  const size_t boff = (size_t)(n0 + srow) * K + sj8;
  const int dstE = w << 9;                   // wave-uniform LDS base (elems), lane*16B implicit

  // frag ds_read de-swizzle: logical chunk (s*4+q) lives at ((s*4+q)^(row&7)); row&7==lr&7
  const int ch0 = ((q ^ l7) << 3);
  const int ch1 = (((4 | q) ^ l7) << 3);

  const int NT = K >> 6;
  const int mg = w >> 2;                     // A half (rows 0-127 / 128-255)
  const int ng = w & 3;                      // B col group (48 cols each)
  const u16* BsBase0 = &smB[0][ng * 3072];   // ng*48 rows * 64 elems
  const u16* BsBase1 = &smB[1][ng * 3072];

  floatx4 acc[8][3];
  #pragma unroll
  for (int i = 0; i < 8; ++i)
    #pragma unroll
    for (int j = 0; j < 3; ++j)
      #pragma unroll
      for (int k = 0; k < 4; ++k) acc[i][j][k] = 0.f;

  // staging macros: R = 64-row round; DB = buffer; KT = k elem offset
#define STGA(R, DB, KT)                                                           \
  async16(A + aoff + (size_t)((R) << 6) * K + (KT),                               \
          &smA[DB][(R) >> 1][(((R) & 1) << 12) + dstE])
#define STGB(R, DB, KT)                                                           \
  async16(B + boff + (size_t)((R) << 6) * K + (KT), &smB[DB][((R) << 12) + dstE])

  // prologue: A(0)x4 + B(0)x3 -> buf0; B(1)x3 -> buf1; wait all but newest 3
  STGA(0, 0, 0); STGA(1, 0, 0); STGA(2, 0, 0); STGA(3, 0, 0);
  STGB(0, 0, 0); STGB(1, 0, 0); STGB(2, 0, 0);
  STGB(0, 1, 64); STGB(1, 1, 64); STGB(2, 1, 64);
  asm volatile("s_waitcnt vmcnt(3)" ::: "memory");
  __builtin_amdgcn_s_barrier();

  for (int kt = 0; kt < NT; ++kt) {
    const int cur = kt & 1;
    const int kt1 = ((kt + 1 < NT) ? kt + 1 : NT - 1) << 6;   // clamp keeps ledger uniform
    const int kt2 = ((kt + 2 < NT) ? kt + 2 : NT - 1) << 6;
    const u16* As0 = &smA[cur][mg][0];
    const u16* Bs  = cur ? BsBase1 : BsBase0;

    short8 a0[4][2], a1[4][2], bf[3][2];

    // ---- ph1: read A0 (local rows 0-63) + B (all 3 col-frags); stage A(t+1)x4; MFMA i=0..3
    #pragma unroll
    for (int i = 0; i < 4; ++i) {
      a0[i][0] = *(const short8*)&As0[(((i << 4) + lr) << 6) + ch0];
      a0[i][1] = *(const short8*)&As0[(((i << 4) + lr) << 6) + ch1];
    }
    #pragma unroll
    for (int j = 0; j < 3; ++j) {
      bf[j][0] = *(const short8*)&Bs[(((j << 4) + lr) << 6) + ch0];
      bf[j][1] = *(const short8*)&Bs[(((j << 4) + lr) << 6) + ch1];
    }
    if (cur) { STGA(0, 0, kt1); STGA(1, 0, kt1); STGA(2, 0, kt1); STGA(3, 0, kt1); }
    else     { STGA(0, 1, kt1); STGA(1, 1, kt1); STGA(2, 1, kt1); STGA(3, 1, kt1); }
    __builtin_amdgcn_s_setprio(1);
    #pragma unroll
    for (int i = 0; i < 4; ++i)
      #pragma unroll
      for (int j = 0; j < 3; ++j) {
        MFMA16(acc[i][j], a0[i][0], bf[j][0]);
        MFMA16(acc[i][j], a0[i][1], bf[j][1]);
      }
    __builtin_amdgcn_s_setprio(0);
    __builtin_amdgcn_s_barrier();
    // all B reads of buf[cur] complete from here on

    // ---- ph2: read A1 (local rows 64-127); stage B(t+2)x3 -> buf[cur]; MFMA i=4..7
    #pragma unroll
    for (int i = 0; i < 4; ++i) {
      a1[i][0] = *(const short8*)&As0[((64 + (i << 4) + lr) << 6) + ch0];
      a1[i][1] = *(const short8*)&As0[((64 + (i << 4) + lr) << 6) + ch1];
    }
    if (cur) { STGB(0, 1, kt2); STGB(1, 1, kt2); STGB(2, 1, kt2); }
    else     { STGB(0, 0, kt2); STGB(1, 0, kt2); STGB(2, 0, kt2); }
    __builtin_amdgcn_s_setprio(1);
    #pragma unroll
    for (int i = 0; i < 4; ++i)
      #pragma unroll
      for (int j = 0; j < 3; ++j) {
        MFMA16(acc[i + 4][j], a1[i][0], bf[j][0]);
        MFMA16(acc[i + 4][j], a1[i][1], bf[j][1]);
      }
    __builtin_amdgcn_s_setprio(0);
    asm volatile("s_waitcnt vmcnt(3)" ::: "memory");   // A(t+1)+B(t+1) landed; B(t+2) in flight
    __builtin_amdgcn_s_barrier();
  }
#undef STGA
#undef STGB

  asm volatile("s_waitcnt vmcnt(0)" ::: "memory");     // drain clamped tail stages

  // epilogue: C/D layout col = lane&15, row = (lane>>4)*4 + reg
  const int wrm = m0 + (mg << 7);
  const int wcn = n0 + ng * 48;
  const int lq = q << 2;
  #pragma unroll
  for (int j = 0; j < 3; ++j) {
    const int cn = wcn + (j << 4) + lr;
    const float bv = bias[cn];
    #pragma unroll
    for (int i = 0; i < 8; ++i) {
      const int rm = wrm + (i << 4) + lq;
      #pragma unroll
      for (int rr = 0; rr < 4; ++rr) {
        float v = acc[i][j][rr] + bv;
        if constexpr (std::is_same<OutT, u16>::value) C[(size_t)(rm + rr) * N + cn] = f2bf(v);
        else                                          C[(size_t)(rm + rr) * N + cn] = v;
      }
    }
  }
}

// ---------------- 256x128 4-phase bf16 GEMM (out-projection, N=1024), BK=64 ----------------
// Verified r2 kernel, unchanged: grid (8192/256)*(1024/128) = 256 = exactly 1 round.
template <typename OutT>
__global__ __launch_bounds__(512, 2)
void k_gemm_2p(const u16* __restrict__ A, const u16* __restrict__ B,
               const float* __restrict__ bias, OutT* __restrict__ C,
               int M, int N, int K) {
  __shared__ __align__(16) u16 sm[2][3][8192];
  const int t = threadIdx.x;
  const int w = t >> 6, lane = t & 63;
  const int lr = lane & 15, q = lane >> 4, l7 = lr & 7;

  const int cpx = (int)gridDim.x >> 3;
  const int wg = ((int)blockIdx.x & 7) * cpx + ((int)blockIdx.x >> 3);
  const int nbx = N >> 7;
  const int by = wg / nbx, bx = wg - by * nbx;
  const int m0 = by << 8, n0 = bx << 7;

  const int srow = t >> 3;
  const int sj8 = (((t & 7) ^ (srow & 7)) << 3);
  const size_t aoff = (size_t)(m0 + srow) * K + sj8;
  const size_t boff = (size_t)(n0 + srow) * K + sj8;
  const int dstE = w << 9;

  const int ch0 = ((q ^ l7) << 3);
  const int ch1 = (((4 | q) ^ l7) << 3);
  const int arow = lr << 6;

  const int NT = K >> 6;
  const int mg = w >> 2;
  const int ng = w & 3;
  const int bbase = ng << 11;

  floatx4 acc[8][2];
  #pragma unroll
  for (int i = 0; i < 8; ++i)
    #pragma unroll
    for (int j = 0; j < 2; ++j)
      #pragma unroll
      for (int k = 0; k < 4; ++k) acc[i][j][k] = 0.f;

#define STG(MAT, R, DB, KT)                                                       \
  async16((MAT ? B : A) + (MAT ? boff : aoff) + (size_t)((R) << 6) * K + (KT),    \
          &sm[DB][(MAT) ? 2 : ((R) >> 1)][(((R) & 1) << 12) + dstE])

  STG(0, 0, 0, 0); STG(0, 1, 0, 0); STG(0, 2, 0, 0); STG(0, 3, 0, 0);
  STG(1, 0, 0, 0); STG(1, 1, 0, 0);
  STG(1, 0, 1, 64); STG(1, 1, 1, 64);
  asm volatile("s_waitcnt vmcnt(2)" ::: "memory");
  __builtin_amdgcn_s_barrier();

  for (int kt = 0; kt < NT; ++kt) {
    const int cur = kt & 1;
    const int kt1 = ((kt + 1 < NT) ? kt + 1 : NT - 1) << 6;
    const int kt2 = ((kt + 2 < NT) ? kt + 2 : NT - 1) << 6;
    const u16* As0 = &sm[cur][mg][0];
    const u16* Bs  = &sm[cur][2][bbase];

    short8 a0[4][2], a1[4][2], bf[2][2];

    #pragma unroll
    for (int i = 0; i < 4; ++i) {
      a0[i][0] = *(const short8*)&As0[(i << 10) + arow + ch0];
      a0[i][1] = *(const short8*)&As0[(i << 10) + arow + ch1];
    }
    #pragma unroll
    for (int j = 0; j < 2; ++j) {
      bf[j][0] = *(const short8*)&Bs[(j << 10) + arow + ch0];
      bf[j][1] = *(const short8*)&Bs[(j << 10) + arow + ch1];
    }
    STG(0, 0, cur ^ 1, kt1); STG(0, 1, cur ^ 1, kt1);
    __builtin_amdgcn_s_setprio(1);
    #pragma unroll
    for (int i = 0; i < 4; ++i) {
      MFMA16(acc[i][0], a0[i][0], bf[0][0]);
      MFMA16(acc[i][0], a0[i][1], bf[0][1]);
    }
    __builtin_amdgcn_s_setprio(0);
    __builtin_amdgcn_s_barrier();

    STG(0, 2, cur ^ 1, kt1); STG(0, 3, cur ^ 1, kt1);
    __builtin_amdgcn_s_setprio(1);
    #pragma unroll
    for (int i = 0; i < 4; ++i) {
      MFMA16(acc[i][1], a0[i][0], bf[1][0]);
      MFMA16(acc[i][1], a0[i][1], bf[1][1]);
    }
    __builtin_amdgcn_s_setprio(0);
    __builtin_amdgcn_s_barrier();

    #pragma unroll
    for (int i = 0; i < 4; ++i) {
      a1[i][0] = *(const short8*)&As0[((i + 4) << 10) + arow + ch0];
      a1[i][1] = *(const short8*)&As0[((i + 4) << 10) + arow + ch1];
    }
    STG(1, 0, cur, kt2);
    __builtin_amdgcn_s_setprio(1);
    #pragma unroll
    for (int i = 0; i < 4; ++i) {
      MFMA16(acc[i + 4][1], a1[i][0], bf[1][0]);
      MFMA16(acc[i + 4][1], a1[i][1], bf[1][1]);
    }
    __builtin_amdgcn_s_setprio(0);
    __builtin_amdgcn_s_barrier();

    STG(1, 1, cur, kt2);
    __builtin_amdgcn_s_setprio(1);
    #pragma unroll
    for (int i = 0; i < 4; ++i) {
      MFMA16(acc[i + 4][0], a1[i][0], bf[0][0]);
      MFMA16(acc[i + 4][0], a1[i][1], bf[0][1]);
    }
    __builtin_amdgcn_s_setprio(0);
    asm volatile("s_waitcnt vmcnt(2)" ::: "memory");
    __builtin_amdgcn_s_barrier();
  }
#undef STG

  asm volatile("s_waitcnt vmcnt(0)" ::: "memory");

  const int wrm = m0 + (mg << 7);
  const int wcn = n0 + (ng << 5);
  const int lq = q << 2;
  #pragma unroll
  for (int j = 0; j < 2; ++j) {
    const int cn = wcn + (j << 4) + lr;
    const float bv = bias[cn];
    #pragma unroll
    for (int i = 0; i < 8; ++i) {
      const int rm = wrm + (i << 4) + lq;
      #pragma unroll
      for (int rr = 0; rr < 4; ++rr) {
        float v = acc[i][j][rr] + bv;
        if constexpr (std::is_same<OutT, u16>::value) C[(size_t)(rm + rr) * N + cn] = f2bf(v);
        else                                          C[(size_t)(rm + rr) * N + cn] = v;
      }
    }
  }
}

// ---------------- Gram partials via MFMA + qsum partials ----------------
__global__ __launch_bounds__(256)
void k_gpart2(const u16* __restrict__ QKV, float* __restrict__ Gpart, float* __restrict__ qpart) {
  const int chunk = blockIdx.x;            // 0..7 (256 a each)
  const int nh = blockIdx.y;               // 0..63
  const int n = nh >> 4, h = nh & 15;
  const int t = threadIdx.x, w = t >> 6, lane = t & 63;
  const int lr = lane & 15, lko = (lane >> 4) << 3;

  __shared__ __align__(16) u16 Qt[64 * 264];   // x-major, a-stride-padded (33.8 KB)
  __shared__ float red[256];

  // transpose-in: thread t <-> a_local = t; reads its full 64-dim Q row (8x uint4, 128 B)
  const int a = chunk * 256 + t;
  const uint4* qp = (const uint4*)(QKV + (size_t)(n * 2048 + h * 128 + (a >> 4)) * 3072 + ((t & 15) << 6));
  union { u16 s[8]; uint4 v; } qv[8];
  #pragma unroll
  for (int j = 0; j < 8; ++j) qv[j].v = qp[j];
  #pragma unroll
  for (int j = 0; j < 8; ++j)
    #pragma unroll
    for (int e = 0; e < 8; ++e)
      Qt[(j * 8 + e) * 264 + t] = qv[j].s[e];   // writes: consecutive a per lane -> 2-way, free
  __syncthreads();

  // qsum partial: thread (x = t&63, c = t>>6) sums Qt[x][c*64 .. +63]
  {
    const int x = t & 63, c = t >> 6;
    const u16* base = &Qt[x * 264 + c * 64];
    float s = 0.f;
    #pragma unroll
    for (int k = 0; k < 8; ++k) {
      float f[8]; unpack8(*(const uint4*)(base + k * 8), f);
      #pragma unroll
      for (int e = 0; e < 8; ++e) s += f[e];
    }
    red[t] = s;
  }
  __syncthreads();
  if (t < 64)
    qpart[((size_t)nh * 8 + chunk) * 64 + t] = red[t] + red[t + 64] + red[t + 128] + red[t + 192];

  // Gram: K-loop over 256 a in 8 steps of 32; wave w owns C tile-row i=w
  floatx4 acc[4];
  #pragma unroll
  for (int j = 0; j < 4; ++j)
    #pragma unroll
    for (int k = 0; k < 4; ++k) acc[j][k] = 0.f;
  for (int ks = 0; ks < 8; ++ks) {
    short8 f[4];
    #pragma unroll
    for (int i = 0; i < 4; ++i) f[i] = *(const short8*)&Qt[((i << 4) + lr) * 264 + (ks << 5) + lko];
    #pragma unroll
    for (int j = 0; j < 4; ++j)
      acc[j] = __builtin_amdgcn_mfma_f32_16x16x32_bf16(f[w], f[j], acc[j], 0, 0, 0);
  }
  float* o = Gpart + ((size_t)nh * 8 + chunk) * 4096;
  const int quad = lane >> 4;
  #pragma unroll
  for (int j = 0; j < 4; ++j)
    #pragma unroll
    for (int r = 0; r < 4; ++r)
      o[((w << 4) + (quad << 2) + r) * 64 + (j << 4) + lr] = acc[j][r];
}

// ---------------- fused: G-reduce -> U = K*G (MFMA, LDS) -> Taylor denom/diag -> mid = diag*V ----
__global__ __launch_bounds__(256)
void k_kgd(const u16* __restrict__ QKV, const float* __restrict__ Gpart,
           const float* __restrict__ qpart, u16* __restrict__ mid) {
  const int chunk = blockIdx.x;            // 0..7 (256 a each)
  const int nh = blockIdx.y;               // 0..63
  const int n = nh >> 4, h = nh & 15;
  const int t = threadIdx.x, w = t >> 6, lane = t & 63;
  const int lr = lane & 15, lko = (lane >> 4) << 3;

  __shared__ u16 Gs[4096];                 // bf16 G_h, 64x64 (8 KB)
  __shared__ __align__(16) u16 Us[256 * 72];  // bf16 U rows, padded stride 72 (36.9 KB)
  __shared__ float qs[64];

  // --- stage 0: reduce Gpart (8 chunks) -> Gs bf16; load qs ---
  const float* gp0 = Gpart + (size_t)nh * 8 * 4096;
  #pragma unroll
  for (int i = 0; i < 16; ++i) {
    int e = (i << 8) + t;
    float s = 0.f;
    #pragma unroll
    for (int c = 0; c < 8; ++c) s += gp0[c * 4096 + e];
    Gs[e] = f2bf(s);
  }
  if (t < 64) {
    float s = 0.f;
    #pragma unroll
    for (int rc = 0; rc < 8; ++rc) s += qpart[((size_t)nh * 8 + rc) * 64 + t];
    qs[t] = s;
  }
  __syncthreads();

  // --- stage 1: U = K * G via MFMA (each wave: 64 a-rows x 64 cols) ---
  short8 af[4][2], bfr[4][2];
  #pragma unroll
  for (int i = 0; i < 4; ++i) {
    const int arow = chunk * 16 + (w << 2) + i;         // (a>>4) within head
    const u16* kp = QKV + (size_t)(n * 2048 + h * 128 + arow) * 3072 + 1024 + lr * 64;
    #pragma unroll
    for (int s = 0; s < 2; ++s) af[i][s] = *(const short8*)(kp + s * 32 + lko);
  }
  #pragma unroll
  for (int j = 0; j < 4; ++j)
    #pragma unroll
    for (int s = 0; s < 2; ++s)
      bfr[j][s] = *(const short8*)&Gs[((j << 4) + lr) * 64 + s * 32 + lko];
  floatx4 acc[4][4];
  #pragma unroll
  for (int i = 0; i < 4; ++i)
    #pragma unroll
    for (int j = 0; j < 4; ++j)
      #pragma unroll
      for (int k = 0; k < 4; ++k) acc[i][j][k] = 0.f;
  #pragma unroll
  for (int s = 0; s < 2; ++s)
    #pragma unroll
    for (int i = 0; i < 4; ++i)
      #pragma unroll
      for (int j = 0; j < 4; ++j)
        acc[i][j] = __builtin_amdgcn_mfma_f32_16x16x32_bf16(af[i][s], bfr[j][s], acc[i][j], 0, 0, 0);
  const int rq = (lane >> 4) << 2;
  #pragma unroll
  for (int i = 0; i < 4; ++i)
    #pragma unroll
    for (int j = 0; j < 4; ++j)
      #pragma unroll
      for (int r = 0; r < 4; ++r) {
        int a_local = (w << 6) + (i << 4) + rq + r;     // 0..255
        Us[a_local * 72 + (j << 4) + lr] = f2bf(acc[i][j][r]);
      }
  __syncthreads();

  // --- stage 2: per-thread a: Taylor denom + diag; mid = diag * V ---
  const int b = chunk * 256 + t;           // a within head
  const int R = n * 2048 + h * 128 + (b >> 4);
  const u16* row = QKV + (size_t)R * 3072 + ((b & 15) << 6);
  const uint4* qp = (const uint4*)row;
  const uint4* kp = (const uint4*)(row + 1024);
  const uint4* vp = (const uint4*)(row + 2048);
  const uint4* up = (const uint4*)&Us[t * 72];
  float sbb = 0.f, s1 = 0.f, quad = 0.f;
  #pragma unroll
  for (int xo = 0; xo < 8; ++xo) {
    float kx[8], qx[8], ux[8];
    unpack8(kp[xo], kx); unpack8(qp[xo], qx); unpack8(up[xo], ux);
    #pragma unroll
    for (int xi = 0; xi < 8; ++xi) {
      sbb  += qx[xi] * kx[xi];
      quad += ux[xi] * kx[xi];
      s1   += qs[xo * 8 + xi] * kx[xi];
    }
  }
  const float c1 = 0.0009765625f;  // 1/1024
  float denom = 2048.f + s1 * c1 + 0.5f * quad * c1 * c1;
  float d = expf(sbb * c1) / denom;
  u16* mp = mid + (size_t)R * 1024 + ((b & 15) << 6);
  #pragma unroll
  for (int xo = 0; xo < 8; ++xo) {
    float f[8]; unpack8(vp[xo], f);
    union { u16 s[8]; uint4 v; } o;
    #pragma unroll
    for (int k = 0; k < 8; ++k) o.s[k] = f2bf(f[k] * d);
    *(uint4*)(mp + xo * 8) = o.v;
  }
}

// ---------------- launch ----------------
extern "C" void kernel_launch(void* const* d_in, const int* in_sizes, int n_in,
                              void* d_out, int out_size, void* d_ws, size_t ws_size,
                              hipStream_t stream) {
  (void)in_sizes; (void)n_in; (void)out_size; (void)ws_size;
  const float* X  = (const float*)d_in[0];
  const float* Wq = (const float*)d_in[1];
  const float* bq = (const float*)d_in[2];
  const float* Wk = (const float*)d_in[3];
  const float* bk = (const float*)d_in[4];
  const float* Wv = (const float*)d_in[5];
  const float* bv = (const float*)d_in[6];
  const float* Wo = (const float*)d_in[7];
  const float* bo = (const float*)d_in[8];
  float* out = (float*)d_out;
  char* ws = (char*)d_ws;

  u16*   Xb    = (u16*)(ws + 0);                 // 16 MB (dead after QKV GEMM)
  u16*   mid   = (u16*)(ws + 0);                 // overlays Xb (written after Xb is dead)
  u16*   Wqkvt = (u16*)(ws + 16777216);          //  6 MB
  u16*   Wot   = (u16*)(ws + 23068672);          //  2 MB
  float* bias3 = (float*)(ws + 25165824);        // 12 KB
  u16*   QKV   = (u16*)(ws + 25182208);          // 48 MB (8192 x [Q|K|V])
  float* Gpart = (float*)(ws + 75513856);        //  8 MB
  float* qpart = (float*)(ws + 83902464);        // 128 KB   -> end ~80 MB

  k_prep<<<8192, 256, 0, stream>>>(X, Wq, Wk, Wv, Wo, bq, bk, bv, Xb, Wqkvt, Wot, bias3);
  // QKV GEMM: 256x192 tiles -> grid (8192/256)*(3072/192) = 512 = exactly 2 rounds
  k_gemm_192<u16><<<512, 512, 0, stream>>>(Xb, Wqkvt, bias3, QKV, 8192, 3072, 1024);
  k_gpart2<<<dim3(8, 64), 256, 0, stream>>>(QKV, Gpart, qpart);
  k_kgd<<<dim3(8, 64), 256, 0, stream>>>(QKV, Gpart, qpart, mid);
  // out-projection: 256x128 tiles -> grid 256 = exactly 1 round (verified r2 kernel)
  k_gemm_2p<float><<<256, 512, 0, stream>>>(mid, Wot, bo, out, 8192, 1024, 1024);
}